// Round 7
// baseline (1157.142 us; speedup 1.0000x reference)
//
#include <hip/hip_runtime.h>
#include <hip/hip_bf16.h>

#define H_IMG 224
#define W_IMG 224
#define B_ 4
#define C_ 256
#define M_ 1024
#define N_ 16384
#define HW_ (H_IMG * W_IMG)
#define OH_ 56
#define OW_ 56
#define NT_ (B_ * N_)   // 65536 total points

// ---------------- Kernel A: transpose xyz_feats (B,C,M) -> XT (B,M,C) ------
__global__ __launch_bounds__(1024) void transpose_kernel(
    const float* __restrict__ xyz, float* __restrict__ XT)
{
    __shared__ float tile[32][33];
    int b  = blockIdx.z;
    int c0 = blockIdx.x * 32;
    int m0 = blockIdx.y * 32;
    int tx = threadIdx.x, ty = threadIdx.y;
    tile[ty][tx] = xyz[(b * C_ + c0 + ty) * M_ + m0 + tx];
    __syncthreads();
    XT[(b * M_ + m0 + ty) * C_ + c0 + tx] = tile[tx][ty];
}

// ---------------- Kernel B: per-point top-3 NN + weights + pixel + count ---
// Evidence chain (R1-R5):
//  - threshold = 0.02328125 = 0.02 * 1.1640625 = 2% of max|np_ref| (R0 datum)
//    -> flat tolerance; we need ZERO discrete flips vs the numpy-f32 ref.
//  - R5 (f32 fma-chain dot) == R2 (f64) bit-exact -> np's d2 is neither my
//    ascending separate-muladd chain (R1/R3/R4) nor an fma chain.
//  - np.einsum(optimize=False) -> sum_of_products_contig_two tail for
//    count<8 is a DESCENDING-index fallthrough switch:
//      accum = a2*b2; accum += a1*b1; accum += a0*b0   (separate mul/add)
//    => dot_np = ((pz*cz) + (py*cy)) + (px*cx)  <- THE fix this round.
//  - projection einsum has the same descending tail but (cx*pz + 0*py) +
//    fx*px is the same single-add as my ascending form (commutative, exact 0
//    term) -> pixel path already bit-matched.
//  - np.sum(p*p,-1) small-n pairwise_sum = ascending simple loop -> p2/c2
//    ascending as before.
//  - strict < insertion = stable lowest-index-on-ties (jax.lax.top_k /
//    stable-argsort semantics).
__global__ __launch_bounds__(256) void top3_kernel(
    const float* __restrict__ points, const float* __restrict__ centers,
    const float* __restrict__ Kmat,
    int* __restrict__ pixA, int* __restrict__ idA, float* __restrict__ wA,
    float* __restrict__ cnt)
{
#pragma clang fp contract(off)
    __shared__ float4 cen[M_];   // 16 KB: (cx, cy, cz, |c|^2 ascending order)
    int b = blockIdx.y;
    int n = blockIdx.x * 256 + threadIdx.x;

    for (int i = threadIdx.x; i < M_; i += 256) {
        float cx = centers[(b * M_ + i) * 3 + 0];
        float cy = centers[(b * M_ + i) * 3 + 1];
        float cz = centers[(b * M_ + i) * 3 + 2];
        float c2 = ((cx * cx) + (cy * cy)) + (cz * cz);  // np.sum ascending
        cen[i] = make_float4(cx, cy, cz, c2);
    }
    __syncthreads();

    float px = points[(b * N_ + n) * 3 + 0];
    float py = points[(b * N_ + n) * 3 + 1];
    float pz = points[(b * N_ + n) * 3 + 2];
    float p2 = ((px * px) + (py * py)) + (pz * pz);      // np.sum ascending

    float d0 = 1e30f, d1 = 1e30f, d2v = 1e30f;
    int   i0 = 0, i1 = 0, i2 = 0;
#pragma unroll 4
    for (int m = 0; m < M_; ++m) {
        float4 cc = cen[m];                   // uniform addr: LDS broadcast
        // np einsum contig_two tail: DESCENDING index, separate mul/add:
        float dot = ((pz * cc.z) + (py * cc.y)) + (px * cc.x);
        float d   = (p2 + cc.w) - (2.0f * dot);
        if (d < d2v) {                        // strict <: lowest index on ties
            if (d < d1) {
                d2v = d1; i2 = i1;
                if (d < d0) { d1 = d0; i1 = i0; d0 = d; i0 = m; }
                else        { d1 = d;  i1 = m; }
            } else { d2v = d; i2 = m; }
        }
    }

    float w0 = 1.0f / (d0  + 1e-8f);
    float w1 = 1.0f / (d1  + 1e-8f);
    float w2 = 1.0f / (d2v + 1e-8f);
    float ws = (w0 + w1) + w2;
    w0 /= ws; w1 /= ws; w2 /= ws;

    // projection: order-invariant (single add of two products; 0*py exact)
    float fx = Kmat[0], cxk = Kmat[2], fy = Kmat[4], cyk = Kmat[5];
    float u_num = (cxk * pz) + (fx * px);
    float v_num = (cyk * pz) + (fy * py);
    float zc    = fmaxf(pz, 1e-8f);
    float u = floorf(u_num / zc);
    float v = floorf(v_num / zc);
    int ui = (int)fminf(fmaxf(u, 0.0f), (float)(W_IMG - 1));
    int vi = (int)fminf(fmaxf(v, 0.0f), (float)(H_IMG - 1));
    int pix = vi * W_IMG + ui;

    int g = b * N_ + n;
    pixA[g] = pix;
    idA[g]           = i0; idA[g + NT_]     = i1; idA[g + 2 * NT_] = i2;
    wA [g]           = w0; wA [g + NT_]     = w1; wA [g + 2 * NT_] = w2;
    atomicAdd(&cnt[b * HW_ + pix], 1.0f);
}

// ---------------- Kernel C: interp + fused normalize + avg-pool scatter ----
__global__ __launch_bounds__(256) void scatter_kernel(
    const float* __restrict__ XT, const int* __restrict__ pixA,
    const int* __restrict__ idA, const float* __restrict__ wA,
    const float* __restrict__ cnt, float* __restrict__ out)
{
    int c = threadIdx.x;          // channel
    int g = blockIdx.x;           // global point id
    int b = g >> 14;              // N_ = 16384

    int   pix = pixA[g];
    int   i0  = idA[g], i1 = idA[g + NT_], i2 = idA[g + 2 * NT_];
    float w0  = wA[g],  w1 = wA[g + NT_],  w2 = wA[g + 2 * NT_];
    float cc  = cnt[b * HW_ + pix];
    float s   = 0.0625f / fmaxf(cc, 1.0f);   // 1/(16*max(count,1))

    const float* r0 = XT + (size_t)(b * M_ + i0) * C_;
    const float* r1 = XT + (size_t)(b * M_ + i1) * C_;
    const float* r2 = XT + (size_t)(b * M_ + i2) * C_;
    float interp = w0 * r0[c] + w1 * r1[c] + w2 * r2[c];

    int u = pix % W_IMG, v = pix / W_IMG;
    int blk = (v >> 2) * OW_ + (u >> 2);
    atomicAdd(&out[(size_t)(b * C_ + c) * (OH_ * OW_) + blk], interp * s);
}

extern "C" void kernel_launch(void* const* d_in, const int* in_sizes, int n_in,
                              void* d_out, int out_size, void* d_ws, size_t ws_size,
                              hipStream_t stream)
{
    const float* xyz_feats = (const float*)d_in[0];  // (B,C,M)
    const float* points    = (const float*)d_in[1];  // (B,N,3)
    const float* centers   = (const float*)d_in[2];  // (B,M,3)
    const float* Kmat      = (const float*)d_in[3];  // (3,3)
    // d_in[4] = kernel_size (=4, compile-time constant here)

    float* out = (float*)d_out;

    // workspace layout
    float* XT   = (float*)d_ws;                  // B*M*C   = 1,048,576 f
    float* cnt  = XT + (size_t)B_ * M_ * C_;     // B*H*W   =   200,704 f
    int*   pixA = (int*)(cnt + (size_t)B_ * HW_);//             65,536 i
    int*   idA  = pixA + NT_;                    //          3× 65,536 i
    float* wA   = (float*)(idA + 3 * NT_);       //          3× 65,536 f

    hipMemsetAsync(out, 0, (size_t)out_size * sizeof(float), stream);
    hipMemsetAsync(cnt, 0, (size_t)B_ * HW_ * sizeof(float), stream);

    dim3 tb(32, 32);
    dim3 tg(C_ / 32, M_ / 32, B_);
    transpose_kernel<<<tg, tb, 0, stream>>>(xyz_feats, XT);

    dim3 bg(N_ / 256, B_);
    top3_kernel<<<bg, 256, 0, stream>>>(points, centers, Kmat, pixA, idA, wA, cnt);

    scatter_kernel<<<NT_, 256, 0, stream>>>(XT, pixA, idA, wA, cnt, out);
}

// Round 8
// 422.575 us; speedup vs baseline: 2.7383x; 2.7383x over previous
//
#include <hip/hip_runtime.h>
#include <hip/hip_bf16.h>

#define H_IMG 224
#define W_IMG 224
#define B_ 4
#define C_ 256
#define M_ 1024
#define N_ 16384
#define HW_ (H_IMG * W_IMG)
#define OH_ 56
#define OW_ 56
#define NBLK_ (OH_ * OW_)        // 3136 pool blocks per batch
#define NBINS_ (B_ * NBLK_)      // 12544 total bins
#define NT_ (B_ * N_)            // 65536 total points

// ---------------- Kernel A: transpose xyz_feats (B,C,M) -> XT (B,M,C) ------
__global__ __launch_bounds__(1024) void transpose_kernel(
    const float* __restrict__ xyz, float* __restrict__ XT)
{
    __shared__ float tile[32][33];
    int b  = blockIdx.z;
    int c0 = blockIdx.x * 32;
    int m0 = blockIdx.y * 32;
    int tx = threadIdx.x, ty = threadIdx.y;
    tile[ty][tx] = xyz[(b * C_ + c0 + ty) * M_ + m0 + tx];
    __syncthreads();
    XT[(b * M_ + m0 + ty) * C_ + c0 + tx] = tile[tx][ty];
}

// ---------------- Kernel B: per-point top-3 NN + weights + pixel + count ---
// NUMERICS LOCKED (R7 pass): np ref einsum tail is DESCENDING-index separate
// mul/add: dot = ((pz*cz)+(py*cy))+(px*cx); p2/c2 ascending; d=(p2+c2)-2*dot;
// contract(off); strict-< stable top-3; projection order-invariant.
// DO NOT change any decision arithmetic here.
__global__ __launch_bounds__(256) void top3_kernel(
    const float* __restrict__ points, const float* __restrict__ centers,
    const float* __restrict__ Kmat,
    int* __restrict__ pixA, int* __restrict__ idA, float* __restrict__ wA,
    float* __restrict__ cnt, int* __restrict__ binCnt)
{
#pragma clang fp contract(off)
    __shared__ float4 cen[M_];   // 16 KB: (cx, cy, cz, |c|^2 ascending order)
    int b = blockIdx.y;
    int n = blockIdx.x * 256 + threadIdx.x;

    for (int i = threadIdx.x; i < M_; i += 256) {
        float cx = centers[(b * M_ + i) * 3 + 0];
        float cy = centers[(b * M_ + i) * 3 + 1];
        float cz = centers[(b * M_ + i) * 3 + 2];
        float c2 = ((cx * cx) + (cy * cy)) + (cz * cz);  // np.sum ascending
        cen[i] = make_float4(cx, cy, cz, c2);
    }
    __syncthreads();

    float px = points[(b * N_ + n) * 3 + 0];
    float py = points[(b * N_ + n) * 3 + 1];
    float pz = points[(b * N_ + n) * 3 + 2];
    float p2 = ((px * px) + (py * py)) + (pz * pz);      // np.sum ascending

    float d0 = 1e30f, d1 = 1e30f, d2v = 1e30f;
    int   i0 = 0, i1 = 0, i2 = 0;
#pragma unroll 4
    for (int m = 0; m < M_; ++m) {
        float4 cc = cen[m];                   // uniform addr: LDS broadcast
        float dot = ((pz * cc.z) + (py * cc.y)) + (px * cc.x); // np tail order
        float d   = (p2 + cc.w) - (2.0f * dot);
        if (d < d2v) {                        // strict <: lowest index on ties
            if (d < d1) {
                d2v = d1; i2 = i1;
                if (d < d0) { d1 = d0; i1 = i0; d0 = d; i0 = m; }
                else        { d1 = d;  i1 = m; }
            } else { d2v = d; i2 = m; }
        }
    }

    float w0 = 1.0f / (d0  + 1e-8f);
    float w1 = 1.0f / (d1  + 1e-8f);
    float w2 = 1.0f / (d2v + 1e-8f);
    float ws = (w0 + w1) + w2;
    w0 /= ws; w1 /= ws; w2 /= ws;

    // projection: order-invariant (single add of two products; 0*py exact)
    float fx = Kmat[0], cxk = Kmat[2], fy = Kmat[4], cyk = Kmat[5];
    float u_num = (cxk * pz) + (fx * px);
    float v_num = (cyk * pz) + (fy * py);
    float zc    = fmaxf(pz, 1e-8f);
    float u = floorf(u_num / zc);
    float v = floorf(v_num / zc);
    int ui = (int)fminf(fmaxf(u, 0.0f), (float)(W_IMG - 1));
    int vi = (int)fminf(fmaxf(v, 0.0f), (float)(H_IMG - 1));
    int pix = vi * W_IMG + ui;

    int g = b * N_ + n;
    pixA[g] = pix;
    idA[g]           = i0; idA[g + NT_]     = i1; idA[g + 2 * NT_] = i2;
    wA [g]           = w0; wA [g + NT_]     = w1; wA [g + 2 * NT_] = w2;
    atomicAdd(&cnt[b * HW_ + pix], 1.0f);
    int bin = b * NBLK_ + (vi >> 2) * OW_ + (ui >> 2);
    atomicAdd(&binCnt[bin], 1);
}

// ---------------- Kernel S: exclusive prefix scan over 12544 bin counts ----
__global__ __launch_bounds__(1024) void scan_kernel(
    const int* __restrict__ binCnt, int* __restrict__ binOff)
{
    const int PER = (NBINS_ + 1023) / 1024;   // 13
    __shared__ int partial[1024];
    int t = threadIdx.x;
    int base = t * PER;
    int local[PER];
    int s = 0;
#pragma unroll
    for (int j = 0; j < PER; ++j) {
        int idx = base + j;
        int v = (idx < NBINS_) ? binCnt[idx] : 0;
        local[j] = s;
        s += v;
    }
    partial[t] = s;
    __syncthreads();
    // Hillis-Steele inclusive scan over 1024 partials
    for (int ofs = 1; ofs < 1024; ofs <<= 1) {
        int v = (t >= ofs) ? partial[t - ofs] : 0;
        __syncthreads();
        partial[t] += v;
        __syncthreads();
    }
    int excl = (t == 0) ? 0 : partial[t - 1];
#pragma unroll
    for (int j = 0; j < PER; ++j) {
        int idx = base + j;
        if (idx < NBINS_) binOff[idx] = excl + local[j];
    }
}

// ---------------- Kernel P: pack points into bin order, pre-scale weights --
// idP[slot] = (i0,i1,i2,b); wP[slot] = (w0*s, w1*s, w2*s, _), s=1/(16*max(cnt,1))
__global__ __launch_bounds__(256) void pack_kernel(
    const int* __restrict__ pixA, const int* __restrict__ idA,
    const float* __restrict__ wA, const float* __restrict__ cnt,
    const int* __restrict__ binOff, int* __restrict__ binFill,
    int4* __restrict__ idP, float4* __restrict__ wP)
{
    int g = blockIdx.x * 256 + threadIdx.x;
    int b = g >> 14;                     // N_ = 16384
    int pix = pixA[g];
    int u = pix % W_IMG, v = pix / W_IMG;
    int bin = b * NBLK_ + (v >> 2) * OW_ + (u >> 2);
    int pos = atomicAdd(&binFill[bin], 1);
    int dst = binOff[bin] + pos;
    float s = 0.0625f / fmaxf(cnt[b * HW_ + pix], 1.0f);
    idP[dst] = make_int4(idA[g], idA[g + NT_], idA[g + 2 * NT_], b);
    wP[dst]  = make_float4(wA[g] * s, wA[g + NT_] * s, wA[g + 2 * NT_] * s, 0.0f);
}

// ---------------- Kernel G: per-bin gather-reduce, atomic-free store -------
// grid = (NBLK_, B_), block = 256 (one thread per channel). Replaces the
// R7 scatter whose 16.7M f32 atomics wrote 512 MB through L2 (965 us).
__global__ __launch_bounds__(256) void gather_kernel(
    const float* __restrict__ XT, const int* __restrict__ binOff,
    const int* __restrict__ binCnt, const int4* __restrict__ idP,
    const float4* __restrict__ wP, float* __restrict__ out)
{
    int blk = blockIdx.x;
    int b   = blockIdx.y;
    int c   = threadIdx.x;
    int bin = b * NBLK_ + blk;
    int off = binOff[bin];
    int k   = binCnt[bin];

    const float* XTb = XT + (size_t)b * M_ * C_;
    float acc = 0.0f;
    for (int j = 0; j < k; ++j) {
        int4   id = idP[off + j];       // uniform across lanes: 1 fetch/wave
        float4 w  = wP[off + j];
        acc += w.x * XTb[(size_t)id.x * C_ + c]
             + w.y * XTb[(size_t)id.y * C_ + c]
             + w.z * XTb[(size_t)id.z * C_ + c];
    }
    out[((size_t)(b * C_ + c)) * NBLK_ + blk] = acc;
}

extern "C" void kernel_launch(void* const* d_in, const int* in_sizes, int n_in,
                              void* d_out, int out_size, void* d_ws, size_t ws_size,
                              hipStream_t stream)
{
    const float* xyz_feats = (const float*)d_in[0];  // (B,C,M)
    const float* points    = (const float*)d_in[1];  // (B,N,3)
    const float* centers   = (const float*)d_in[2];  // (B,M,3)
    const float* Kmat      = (const float*)d_in[3];  // (3,3)

    float* out = (float*)d_out;

    // workspace layout (~9.1 MB)
    float* XT     = (float*)d_ws;                    // 4 MB
    float* cnt    = XT + (size_t)B_ * M_ * C_;       // 0.8 MB
    int*   pixA   = (int*)(cnt + (size_t)B_ * HW_);  // 256 KB
    int*   idA    = pixA + NT_;                      // 768 KB
    float* wA     = (float*)(idA + 3 * NT_);         // 768 KB
    int*   binCnt = (int*)(wA + 3 * NT_);            // 50 KB
    int*   binOff = binCnt + NBINS_;                 // 50 KB
    int*   binFill= binOff + NBINS_;                 // 50 KB
    int4*  idP    = (int4*)(binFill + NBINS_);       // 1 MB
    float4* wP    = (float4*)(idP + NT_);            // 1 MB

    hipMemsetAsync(cnt, 0, (size_t)B_ * HW_ * sizeof(float), stream);
    hipMemsetAsync(binCnt, 0, NBINS_ * sizeof(int), stream);
    hipMemsetAsync(binFill, 0, NBINS_ * sizeof(int), stream);

    dim3 tb(32, 32);
    dim3 tg(C_ / 32, M_ / 32, B_);
    transpose_kernel<<<tg, tb, 0, stream>>>(xyz_feats, XT);

    dim3 bg(N_ / 256, B_);
    top3_kernel<<<bg, 256, 0, stream>>>(points, centers, Kmat,
                                        pixA, idA, wA, cnt, binCnt);

    scan_kernel<<<1, 1024, 0, stream>>>(binCnt, binOff);

    pack_kernel<<<NT_ / 256, 256, 0, stream>>>(pixA, idA, wA, cnt,
                                               binOff, binFill, idP, wP);

    dim3 gg(NBLK_, B_);
    gather_kernel<<<gg, 256, 0, stream>>>(XT, binOff, binCnt, idP, wP, out);
}

// Round 9
// 268.773 us; speedup vs baseline: 4.3053x; 1.5722x over previous
//
#include <hip/hip_runtime.h>
#include <hip/hip_bf16.h>

#define H_IMG 224
#define W_IMG 224
#define B_ 4
#define C_ 256
#define M_ 1024
#define N_ 16384
#define HW_ (H_IMG * W_IMG)
#define OH_ 56
#define OW_ 56
#define NBLK_ (OH_ * OW_)        // 3136 pool blocks per batch
#define NBINS_ (B_ * NBLK_)      // 12544 total bins
#define NT_ (B_ * N_)            // 65536 total points
#define SEG_ 32                  // max points per gather segment
#define MAXSEG_ (NBINS_ + NT_ / SEG_)   // 14592 upper bound

// ---------------- Kernel A: transpose xyz_feats (B,C,M) -> XT (B,M,C) ------
__global__ __launch_bounds__(1024) void transpose_kernel(
    const float* __restrict__ xyz, float* __restrict__ XT)
{
    __shared__ float tile[32][33];
    int b  = blockIdx.z;
    int c0 = blockIdx.x * 32;
    int m0 = blockIdx.y * 32;
    int tx = threadIdx.x, ty = threadIdx.y;
    tile[ty][tx] = xyz[(b * C_ + c0 + ty) * M_ + m0 + tx];
    __syncthreads();
    XT[(b * M_ + m0 + ty) * C_ + c0 + tx] = tile[tx][ty];
}

// ---------------- Kernel B: per-point top-3 NN + weights + pixel + count ---
// NUMERICS LOCKED (R7 pass): np ref einsum tail is DESCENDING-index separate
// mul/add: dot = ((pz*cz)+(py*cy))+(px*cx); p2/c2 ascending; d=(p2+c2)-2*dot;
// contract(off); strict-< stable top-3; projection order-invariant.
// DO NOT change any decision arithmetic here.
__global__ __launch_bounds__(256) void top3_kernel(
    const float* __restrict__ points, const float* __restrict__ centers,
    const float* __restrict__ Kmat,
    int* __restrict__ pixA, int* __restrict__ idA, float* __restrict__ wA,
    float* __restrict__ cnt, int* __restrict__ binCnt)
{
#pragma clang fp contract(off)
    __shared__ float4 cen[M_];   // 16 KB: (cx, cy, cz, |c|^2 ascending order)
    int b = blockIdx.y;
    int n = blockIdx.x * 256 + threadIdx.x;

    for (int i = threadIdx.x; i < M_; i += 256) {
        float cx = centers[(b * M_ + i) * 3 + 0];
        float cy = centers[(b * M_ + i) * 3 + 1];
        float cz = centers[(b * M_ + i) * 3 + 2];
        float c2 = ((cx * cx) + (cy * cy)) + (cz * cz);  // np.sum ascending
        cen[i] = make_float4(cx, cy, cz, c2);
    }
    __syncthreads();

    float px = points[(b * N_ + n) * 3 + 0];
    float py = points[(b * N_ + n) * 3 + 1];
    float pz = points[(b * N_ + n) * 3 + 2];
    float p2 = ((px * px) + (py * py)) + (pz * pz);      // np.sum ascending

    float d0 = 1e30f, d1 = 1e30f, d2v = 1e30f;
    int   i0 = 0, i1 = 0, i2 = 0;
#pragma unroll 4
    for (int m = 0; m < M_; ++m) {
        float4 cc = cen[m];                   // uniform addr: LDS broadcast
        float dot = ((pz * cc.z) + (py * cc.y)) + (px * cc.x); // np tail order
        float d   = (p2 + cc.w) - (2.0f * dot);
        if (d < d2v) {                        // strict <: lowest index on ties
            if (d < d1) {
                d2v = d1; i2 = i1;
                if (d < d0) { d1 = d0; i1 = i0; d0 = d; i0 = m; }
                else        { d1 = d;  i1 = m; }
            } else { d2v = d; i2 = m; }
        }
    }

    float w0 = 1.0f / (d0  + 1e-8f);
    float w1 = 1.0f / (d1  + 1e-8f);
    float w2 = 1.0f / (d2v + 1e-8f);
    float ws = (w0 + w1) + w2;
    w0 /= ws; w1 /= ws; w2 /= ws;

    // projection: order-invariant (single add of two products; 0*py exact)
    float fx = Kmat[0], cxk = Kmat[2], fy = Kmat[4], cyk = Kmat[5];
    float u_num = (cxk * pz) + (fx * px);
    float v_num = (cyk * pz) + (fy * py);
    float zc    = fmaxf(pz, 1e-8f);
    float u = floorf(u_num / zc);
    float v = floorf(v_num / zc);
    int ui = (int)fminf(fmaxf(u, 0.0f), (float)(W_IMG - 1));
    int vi = (int)fminf(fmaxf(v, 0.0f), (float)(H_IMG - 1));
    int pix = vi * W_IMG + ui;

    int g = b * N_ + n;
    pixA[g] = pix;
    idA[g]           = i0; idA[g + NT_]     = i1; idA[g + 2 * NT_] = i2;
    wA [g]           = w0; wA [g + NT_]     = w1; wA [g + 2 * NT_] = w2;
    atomicAdd(&cnt[b * HW_ + pix], 1.0f);
    int bin = b * NBLK_ + (vi >> 2) * OW_ + (ui >> 2);
    atomicAdd(&binCnt[bin], 1);
}

// ---------------- Kernel S: exclusive prefix scan over 12544 bin counts ----
__global__ __launch_bounds__(1024) void scan_kernel(
    const int* __restrict__ binCnt, int* __restrict__ binOff)
{
    const int PER = (NBINS_ + 1023) / 1024;   // 13
    __shared__ int partial[1024];
    int t = threadIdx.x;
    int base = t * PER;
    int local[PER];
    int s = 0;
#pragma unroll
    for (int j = 0; j < PER; ++j) {
        int idx = base + j;
        int v = (idx < NBINS_) ? binCnt[idx] : 0;
        local[j] = s;
        s += v;
    }
    partial[t] = s;
    __syncthreads();
    for (int ofs = 1; ofs < 1024; ofs <<= 1) {
        int v = (t >= ofs) ? partial[t - ofs] : 0;
        __syncthreads();
        partial[t] += v;
        __syncthreads();
    }
    int excl = (t == 0) ? 0 : partial[t - 1];
#pragma unroll
    for (int j = 0; j < PER; ++j) {
        int idx = base + j;
        if (idx < NBINS_) binOff[idx] = excl + local[j];
    }
}

// ---------------- Kernel SB: build <=SEG_-point segments per bin -----------
// Straggler fix (R8: corner bin ~700 pts => one block ran ~100+us serial,
// OccupancyPercent 11%). Every bin emits max(1,ceil(k/SEG_)) segments.
__global__ __launch_bounds__(256) void segbuild_kernel(
    const int* __restrict__ binCnt, const int* __restrict__ binOff,
    int* __restrict__ segCounter, int4* __restrict__ segs)
{
    int bin = blockIdx.x * 256 + threadIdx.x;
    if (bin >= NBINS_) return;
    int k = binCnt[bin];
    int nseg = (k + SEG_ - 1) / SEG_;
    if (nseg == 0) nseg = 1;                 // empty bins still write out=0
    int base = atomicAdd(segCounter, nseg);
    int off = binOff[bin];
    for (int s = 0; s < nseg; ++s) {
        int len = k - s * SEG_;
        len = (len < 0) ? 0 : ((len > SEG_) ? SEG_ : len);
        segs[base + s] = make_int4(bin, off + s * SEG_, len, nseg);
    }
}

// ---------------- Kernel P: pack points into bin order, pre-scale weights --
__global__ __launch_bounds__(256) void pack_kernel(
    const int* __restrict__ pixA, const int* __restrict__ idA,
    const float* __restrict__ wA, const float* __restrict__ cnt,
    const int* __restrict__ binOff, int* __restrict__ binFill,
    int4* __restrict__ idP, float4* __restrict__ wP)
{
    int g = blockIdx.x * 256 + threadIdx.x;
    int b = g >> 14;                     // N_ = 16384
    int pix = pixA[g];
    int u = pix % W_IMG, v = pix / W_IMG;
    int bin = b * NBLK_ + (v >> 2) * OW_ + (u >> 2);
    int pos = atomicAdd(&binFill[bin], 1);
    int dst = binOff[bin] + pos;
    float s = 0.0625f / fmaxf(cnt[b * HW_ + pix], 1.0f);
    idP[dst] = make_int4(idA[g], idA[g + NT_], idA[g + 2 * NT_], b);
    wP[dst]  = make_float4(wA[g] * s, wA[g + NT_] * s, wA[g + 2 * NT_] * s, 0.0f);
}

// ---------------- Kernel G: per-segment gather-reduce ----------------------
// One block per <=32-point segment. (id,w) staged in LDS so all XT gather
// loads are address-independent (ILP hides L2 latency). Single-segment bins
// plain-store; multi-segment bins atomicAdd into pre-zeroed out (~0.5M
// atomics worst case = 16 MB, vs R7's 16.7M/512 MB).
__global__ __launch_bounds__(256) void gather_kernel(
    const float* __restrict__ XT, const int4* __restrict__ segs,
    const int* __restrict__ segCounter, const int4* __restrict__ idP,
    const float4* __restrict__ wP, float* __restrict__ out)
{
    int sid = blockIdx.x;
    if (sid >= segCounter[0]) return;
    int4 sg   = segs[sid];
    int bin   = sg.x, start = sg.y, len = sg.z, nseg = sg.w;
    int b     = bin / NBLK_;
    int blk   = bin - b * NBLK_;
    int c     = threadIdx.x;

    __shared__ int4   sId[SEG_];
    __shared__ float4 sW [SEG_];
    if (c < len) { sId[c] = idP[start + c]; sW[c] = wP[start + c]; }
    __syncthreads();

    const float* XTb = XT + (size_t)b * (M_ * C_);
    float acc = 0.0f;
    for (int j = 0; j < len; ++j) {
        int4   id = sId[j];               // LDS broadcast
        float4 w  = sW[j];
        acc = fmaf(w.x, XTb[id.x * C_ + c],
              fmaf(w.y, XTb[id.y * C_ + c],
              fmaf(w.z, XTb[id.z * C_ + c], acc)));
    }

    float* dst = &out[((size_t)(b * C_ + c)) * NBLK_ + blk];
    if (nseg == 1) *dst = acc;
    else           atomicAdd(dst, acc);
}

extern "C" void kernel_launch(void* const* d_in, const int* in_sizes, int n_in,
                              void* d_out, int out_size, void* d_ws, size_t ws_size,
                              hipStream_t stream)
{
    const float* xyz_feats = (const float*)d_in[0];  // (B,C,M)
    const float* points    = (const float*)d_in[1];  // (B,N,3)
    const float* centers   = (const float*)d_in[2];  // (B,M,3)
    const float* Kmat      = (const float*)d_in[3];  // (3,3)

    float* out = (float*)d_out;

    // workspace layout (~8.6 MB; 16B-aligned chunks first)
    float*  XT       = (float*)d_ws;                     // 4 MB
    int4*   idP      = (int4*)(XT + (size_t)B_ * M_ * C_);   // 1 MB
    float4* wP       = (float4*)(idP + NT_);             // 1 MB
    int4*   segs     = (int4*)(wP + NT_);                // 228 KB
    float*  cnt      = (float*)(segs + MAXSEG_);         // 784 KB
    int*    pixA     = (int*)(cnt + (size_t)B_ * HW_);   // 256 KB
    int*    idA      = pixA + NT_;                       // 768 KB
    float*  wA       = (float*)(idA + 3 * NT_);          // 768 KB
    int*    binCnt   = (int*)(wA + 3 * NT_);             // 50 KB
    int*    binOff   = binCnt + NBINS_;                  // 50 KB
    int*    binFill  = binOff + NBINS_;                  // 50 KB
    int*    segCounter = binFill + NBINS_;               // 16 B

    hipMemsetAsync(cnt, 0, (size_t)B_ * HW_ * sizeof(float), stream);
    hipMemsetAsync(binCnt, 0, NBINS_ * sizeof(int), stream);
    hipMemsetAsync(binFill, 0, NBINS_ * sizeof(int), stream);
    hipMemsetAsync(segCounter, 0, sizeof(int), stream);
    hipMemsetAsync(out, 0, (size_t)out_size * sizeof(float), stream);

    dim3 tb(32, 32);
    dim3 tg(C_ / 32, M_ / 32, B_);
    transpose_kernel<<<tg, tb, 0, stream>>>(xyz_feats, XT);

    dim3 bg(N_ / 256, B_);
    top3_kernel<<<bg, 256, 0, stream>>>(points, centers, Kmat,
                                        pixA, idA, wA, cnt, binCnt);

    scan_kernel<<<1, 1024, 0, stream>>>(binCnt, binOff);

    segbuild_kernel<<<(NBINS_ + 255) / 256, 256, 0, stream>>>(
        binCnt, binOff, segCounter, segs);

    pack_kernel<<<NT_ / 256, 256, 0, stream>>>(pixA, idA, wA, cnt,
                                               binOff, binFill, idP, wP);

    gather_kernel<<<MAXSEG_, 256, 0, stream>>>(XT, segs, segCounter,
                                               idP, wP, out);
}

// Round 10
// 177.956 us; speedup vs baseline: 6.5024x; 1.5103x over previous
//
#include <hip/hip_runtime.h>
#include <hip/hip_bf16.h>

#define H_IMG 224
#define W_IMG 224
#define B_ 4
#define C_ 256
#define M_ 1024
#define N_ 16384
#define HW_ (H_IMG * W_IMG)
#define OH_ 56
#define OW_ 56
#define NBLK_ (OH_ * OW_)        // 3136 pool blocks per batch
#define NBINS_ (B_ * NBLK_)      // 12544 total bins
#define NT_ (B_ * N_)            // 65536 total points
#define SEG_ 32                  // max points per gather segment
#define MAXSEG_ (NBINS_ + NT_ / SEG_)   // 14592 upper bound
#define KS_ 4                    // center-dimension slices in top3
#define MC_ (M_ / KS_)           // 256 centers per slice
// contiguous zero region: tmp + cnt + binCnt + binFill + segCounter
#define ZTOT_ (NBINS_ * C_ + B_ * HW_ + 2 * NBINS_ + 1)

// ------- Kernel A: transpose xyz_feats (B,C,M)->XT (B,M,C) + fused zeroing -
__global__ __launch_bounds__(1024) void transpose_kernel(
    const float* __restrict__ xyz, float* __restrict__ XT,
    float* __restrict__ zeroRegion)
{
    __shared__ float tile[32][33];
    int b  = blockIdx.z;
    int c0 = blockIdx.x * 32;
    int m0 = blockIdx.y * 32;
    int tx = threadIdx.x, ty = threadIdx.y;
    // fused zeroing (replaces 5 hipMemsetAsync launches): 1,048,576 threads
    int flat = ((blockIdx.z * gridDim.y + blockIdx.y) * gridDim.x + blockIdx.x)
               * 1024 + ty * 32 + tx;
    for (int i = flat; i < ZTOT_; i += 1024 * 1024) zeroRegion[i] = 0.0f;
    tile[ty][tx] = xyz[(b * C_ + c0 + ty) * M_ + m0 + tx];
    __syncthreads();
    XT[(b * M_ + m0 + ty) * C_ + c0 + tx] = tile[tx][ty];
}

// ---------------- Kernel B: K-split top-3 NN (1024 thr = 256 pts x 4 slices)
// NUMERICS LOCKED (R7 pass): np ref einsum tail is DESCENDING-index separate
// mul/add: dot = ((pz*cz)+(py*cy))+(px*cx); p2/c2 ascending; d=(p2+c2)-2*dot;
// contract(off); stable top-3 (lowest index on exact ties); projection
// order-invariant. DO NOT change any decision arithmetic.
// R9 fix: grid was 256 blocks = 1 wave/SIMD, 122us latency-bound. Now each
// block is 1024 threads: slice s scans M/4=256 centers (strict-< insertion =>
// per-slice triple lex-sorted by (d,idx)); merge of 4 triples by full
// lexicographic (d,idx) comparator == global stable top-3.
__global__ __launch_bounds__(1024) void top3_kernel(
    const float* __restrict__ points, const float* __restrict__ centers,
    const float* __restrict__ Kmat,
    int* __restrict__ pixA, int* __restrict__ idA, float* __restrict__ wA,
    float* __restrict__ cnt, int* __restrict__ binCnt)
{
#pragma clang fp contract(off)
    __shared__ float4 cen[M_];           // 16 KB
    __shared__ float  pd[KS_][256][3];   // 12 KB partial distances
    __shared__ int    pi[KS_][256][3];   // 12 KB partial indices
    int b = blockIdx.y;
    int t = threadIdx.x;
    int p = t & 255;
    int s = t >> 8;
    int n = blockIdx.x * 256 + p;

    {   // stage centers: one per thread
        float cx = centers[(b * M_ + t) * 3 + 0];
        float cy = centers[(b * M_ + t) * 3 + 1];
        float cz = centers[(b * M_ + t) * 3 + 2];
        float c2 = ((cx * cx) + (cy * cy)) + (cz * cz);  // np.sum ascending
        cen[t] = make_float4(cx, cy, cz, c2);
    }
    __syncthreads();

    float px = points[(b * N_ + n) * 3 + 0];
    float py = points[(b * N_ + n) * 3 + 1];
    float pz = points[(b * N_ + n) * 3 + 2];
    float p2 = ((px * px) + (py * py)) + (pz * pz);      // np.sum ascending

    float d0 = 1e30f, d1 = 1e30f, d2v = 1e30f;
    int   i0 = 0, i1 = 0, i2 = 0;
    int mbase = s * MC_;
#pragma unroll 4
    for (int j = 0; j < MC_; ++j) {
        int m = mbase + j;
        float4 cc = cen[m];               // uniform in wave: LDS broadcast
        float dot = ((pz * cc.z) + (py * cc.y)) + (px * cc.x); // np tail order
        float d   = (p2 + cc.w) - (2.0f * dot);
        if (d < d2v) {                    // strict <: lowest index on ties
            if (d < d1) {
                d2v = d1; i2 = i1;
                if (d < d0) { d1 = d0; i1 = i0; d0 = d; i0 = m; }
                else        { d1 = d;  i1 = m; }
            } else { d2v = d; i2 = m; }
        }
    }
    pd[s][p][0] = d0;  pd[s][p][1] = d1;  pd[s][p][2] = d2v;
    pi[s][p][0] = i0;  pi[s][p][1] = i1;  pi[s][p][2] = i2;
    __syncthreads();

    if (t < 256) {
        // merge 12 candidates, full lexicographic (d, idx): order-independent
        float md0 = 1e30f, md1 = 1e30f, md2 = 1e30f;
        int   mi0 = M_,    mi1 = M_,    mi2 = M_;
#pragma unroll
        for (int ss = 0; ss < KS_; ++ss)
#pragma unroll
            for (int j = 0; j < 3; ++j) {
                float dd = pd[ss][t][j];
                int   ii = pi[ss][t][j];
                if ((dd < md2) || (dd == md2 && ii < mi2)) {
                    if ((dd < md1) || (dd == md1 && ii < mi1)) {
                        md2 = md1; mi2 = mi1;
                        if ((dd < md0) || (dd == md0 && ii < mi0)) {
                            md1 = md0; mi1 = mi0; md0 = dd; mi0 = ii;
                        } else { md1 = dd; mi1 = ii; }
                    } else { md2 = dd; mi2 = ii; }
                }
            }

        float w0 = 1.0f / (md0 + 1e-8f);
        float w1 = 1.0f / (md1 + 1e-8f);
        float w2 = 1.0f / (md2 + 1e-8f);
        float ws = (w0 + w1) + w2;
        w0 /= ws; w1 /= ws; w2 /= ws;

        // projection: order-invariant (single add of two products; 0*py exact)
        float fx = Kmat[0], cxk = Kmat[2], fy = Kmat[4], cyk = Kmat[5];
        float u_num = (cxk * pz) + (fx * px);
        float v_num = (cyk * pz) + (fy * py);
        float zc    = fmaxf(pz, 1e-8f);
        float u = floorf(u_num / zc);
        float v = floorf(v_num / zc);
        int ui = (int)fminf(fmaxf(u, 0.0f), (float)(W_IMG - 1));
        int vi = (int)fminf(fmaxf(v, 0.0f), (float)(H_IMG - 1));
        int pix = vi * W_IMG + ui;

        int g = b * N_ + n;
        pixA[g] = pix;
        idA[g]           = mi0; idA[g + NT_]     = mi1; idA[g + 2 * NT_] = mi2;
        wA [g]           = w0;  wA [g + NT_]     = w1;  wA [g + 2 * NT_] = w2;
        atomicAdd(&cnt[b * HW_ + pix], 1.0f);
        int bin = b * NBLK_ + (vi >> 2) * OW_ + (ui >> 2);
        atomicAdd(&binCnt[bin], 1);
    }
}

// ---------------- Kernel S: exclusive prefix scan over 12544 bin counts ----
__global__ __launch_bounds__(1024) void scan_kernel(
    const int* __restrict__ binCnt, int* __restrict__ binOff)
{
    const int PER = (NBINS_ + 1023) / 1024;   // 13
    __shared__ int partial[1024];
    int t = threadIdx.x;
    int base = t * PER;
    int local[PER];
    int s = 0;
#pragma unroll
    for (int j = 0; j < PER; ++j) {
        int idx = base + j;
        int v = (idx < NBINS_) ? binCnt[idx] : 0;
        local[j] = s;
        s += v;
    }
    partial[t] = s;
    __syncthreads();
    for (int ofs = 1; ofs < 1024; ofs <<= 1) {
        int v = (t >= ofs) ? partial[t - ofs] : 0;
        __syncthreads();
        partial[t] += v;
        __syncthreads();
    }
    int excl = (t == 0) ? 0 : partial[t - 1];
#pragma unroll
    for (int j = 0; j < PER; ++j) {
        int idx = base + j;
        if (idx < NBINS_) binOff[idx] = excl + local[j];
    }
}

// ---------------- Kernel SB: build <=SEG_-point segments per bin -----------
__global__ __launch_bounds__(256) void segbuild_kernel(
    const int* __restrict__ binCnt, const int* __restrict__ binOff,
    int* __restrict__ segCounter, int4* __restrict__ segs)
{
    int bin = blockIdx.x * 256 + threadIdx.x;
    if (bin >= NBINS_) return;
    int k = binCnt[bin];
    int nseg = (k + SEG_ - 1) / SEG_;
    if (nseg == 0) nseg = 1;                 // empty bins still write tmp=0
    int base = atomicAdd(segCounter, nseg);
    int off = binOff[bin];
    for (int s = 0; s < nseg; ++s) {
        int len = k - s * SEG_;
        len = (len < 0) ? 0 : ((len > SEG_) ? SEG_ : len);
        segs[base + s] = make_int4(bin, off + s * SEG_, len, nseg);
    }
}

// ---------------- Kernel P: pack points into bin order, pre-scale weights --
__global__ __launch_bounds__(256) void pack_kernel(
    const int* __restrict__ pixA, const int* __restrict__ idA,
    const float* __restrict__ wA, const float* __restrict__ cnt,
    const int* __restrict__ binOff, int* __restrict__ binFill,
    int4* __restrict__ idP, float4* __restrict__ wP)
{
    int g = blockIdx.x * 256 + threadIdx.x;
    int b = g >> 14;                     // N_ = 16384
    int pix = pixA[g];
    int u = pix % W_IMG, v = pix / W_IMG;
    int bin = b * NBLK_ + (v >> 2) * OW_ + (u >> 2);
    int pos = atomicAdd(&binFill[bin], 1);
    int dst = binOff[bin] + pos;
    float s = 0.0625f / fmaxf(cnt[b * HW_ + pix], 1.0f);
    idP[dst] = make_int4(idA[g], idA[g + NT_], idA[g + 2 * NT_], b);
    wP[dst]  = make_float4(wA[g] * s, wA[g + NT_] * s, wA[g + 2 * NT_] * s, 0.0f);
}

// ---------------- Kernel G: per-segment gather-reduce into bin-major tmp ---
// R9 fix: stores went to channel-major out (stride NBLK_*4B per lane) =>
// WRITE_SIZE 120MB for 12.8MB useful (32B-sector inflation). Now store to
// tmp[bin*C_+c]: 64 consecutive lanes = contiguous 1KB => zero inflation.
__global__ __launch_bounds__(256) void gather_kernel(
    const float* __restrict__ XT, const int4* __restrict__ segs,
    const int* __restrict__ segCounter, const int4* __restrict__ idP,
    const float4* __restrict__ wP, float* __restrict__ tmp)
{
    int sid = blockIdx.x;
    if (sid >= segCounter[0]) return;
    int4 sg   = segs[sid];
    int bin   = sg.x, start = sg.y, len = sg.z, nseg = sg.w;
    int b     = bin / NBLK_;
    int c     = threadIdx.x;

    __shared__ int4   sId[SEG_];
    __shared__ float4 sW [SEG_];
    if (c < len) { sId[c] = idP[start + c]; sW[c] = wP[start + c]; }
    __syncthreads();

    const float* XTb = XT + (size_t)b * (M_ * C_);
    float acc = 0.0f;
    for (int j = 0; j < len; ++j) {
        int4   id = sId[j];               // LDS broadcast
        float4 w  = sW[j];
        acc = fmaf(w.x, XTb[id.x * C_ + c],
              fmaf(w.y, XTb[id.y * C_ + c],
              fmaf(w.z, XTb[id.z * C_ + c], acc)));
    }

    float* dst = &tmp[(size_t)bin * C_ + c];
    if (nseg == 1) *dst = acc;            // covers empty bins (acc = 0)
    else           atomicAdd(dst, acc);   // tmp pre-zeroed in transpose_kernel
}

// ---------------- Kernel U: untranspose tmp (B,NBLK,C) -> out (B,C,NBLK) ---
__global__ __launch_bounds__(1024) void untranspose_kernel(
    const float* __restrict__ tmp, float* __restrict__ out)
{
    __shared__ float tile[32][33];
    int b  = blockIdx.z;
    int n0 = blockIdx.x * 32;   // NBLK_/32 = 98
    int c0 = blockIdx.y * 32;   // C_/32 = 8
    int tx = threadIdx.x, ty = threadIdx.y;
    tile[ty][tx] = tmp[((size_t)b * NBLK_ + n0 + ty) * C_ + c0 + tx];
    __syncthreads();
    out[((size_t)(b * C_ + c0 + ty)) * NBLK_ + n0 + tx] = tile[tx][ty];
}

extern "C" void kernel_launch(void* const* d_in, const int* in_sizes, int n_in,
                              void* d_out, int out_size, void* d_ws, size_t ws_size,
                              hipStream_t stream)
{
    const float* xyz_feats = (const float*)d_in[0];  // (B,C,M)
    const float* points    = (const float*)d_in[1];  // (B,N,3)
    const float* centers   = (const float*)d_in[2];  // (B,M,3)
    const float* Kmat      = (const float*)d_in[3];  // (3,3)

    float* out = (float*)d_out;

    // workspace layout (~21.7 MB)
    float*  XT       = (float*)d_ws;                         // 4 MB
    int4*   idP      = (int4*)(XT + (size_t)B_ * M_ * C_);   // 1 MB
    float4* wP       = (float4*)(idP + NT_);                 // 1 MB
    int4*   segs     = (int4*)(wP + NT_);                    // 228 KB
    float*  tmp      = (float*)(segs + MAXSEG_);             // 12.8 MB (zero rgn)
    float*  cnt      = tmp + (size_t)NBINS_ * C_;            // 784 KB
    int*    binCnt   = (int*)(cnt + (size_t)B_ * HW_);       // 50 KB
    int*    binFill  = binCnt + NBINS_;                      // 50 KB
    int*    segCounter = binFill + NBINS_;                   // 4 B
    int*    pixA     = segCounter + 1;                       // 256 KB
    int*    idA      = pixA + NT_;                           // 768 KB
    float*  wA       = (float*)(idA + 3 * NT_);              // 768 KB
    int*    binOff   = (int*)(wA + 3 * NT_);                 // 50 KB

    dim3 tb(32, 32);
    dim3 tg(C_ / 32, M_ / 32, B_);
    transpose_kernel<<<tg, tb, 0, stream>>>(xyz_feats, XT, tmp);

    dim3 bg(N_ / 256, B_);
    top3_kernel<<<bg, 1024, 0, stream>>>(points, centers, Kmat,
                                         pixA, idA, wA, cnt, binCnt);

    scan_kernel<<<1, 1024, 0, stream>>>(binCnt, binOff);

    segbuild_kernel<<<(NBINS_ + 255) / 256, 256, 0, stream>>>(
        binCnt, binOff, segCounter, segs);

    pack_kernel<<<NT_ / 256, 256, 0, stream>>>(pixA, idA, wA, cnt,
                                               binOff, binFill, idP, wP);

    gather_kernel<<<MAXSEG_, 256, 0, stream>>>(XT, segs, segCounter,
                                               idP, wP, tmp);

    dim3 ug(NBLK_ / 32, C_ / 32, B_);
    untranspose_kernel<<<ug, tb, 0, stream>>>(tmp, out);
}